// Round 15
// baseline (257.173 us; speedup 1.0000x reference)
//
#include <hip/hip_runtime.h>
#include <math.h>

#define NH_TOT 524288   // 4096*128
#define N_ATOM 4096
#define N_EDGE 65536

typedef __attribute__((ext_vector_type(8))) short bf16x8;
typedef __attribute__((ext_vector_type(4))) float f32x4;

__device__ __forceinline__ unsigned short f2bf(float f) {
    unsigned u = __builtin_bit_cast(unsigned, f);
    unsigned r = (u + 0x7fffu + ((u >> 16) & 1u)) >> 16;
    return (unsigned short)r;
}
__device__ __forceinline__ float bf2f(unsigned short s) {
    unsigned u = ((unsigned)s) << 16;
    return __builtin_bit_cast(float, u);
}
__device__ __forceinline__ float silu(float v) { return v / (1.0f + __expf(-v)); }

// wb layout (bf16 elements):
// ls0@0(32768), ls1@32768(98304), lt0@131072(16384), lt1@147456(16384),
// lt2@163840(16384), dp1@180224(4096), dp2@184320(4096), dp3@188416(4096)
#define WB_LS1 32768
#define WB_LT0 131072
#define WB_LT1 147456
#define WB_LT2 163840
#define WB_DP  180224

// ---------------------------------------------------------------------------
// Setup: [0,4096) U1/U2 (one wave per (t,h), coalesced); [4096,4352) edge
// scatter into padded per-node buckets, packing e | z_dst<<16; [4352,4540)
// weight bf16 conversion.
// ---------------------------------------------------------------------------
__global__ __launch_bounds__(256) void k_setup(
    const float* __restrict__ emb_w, const float* __restrict__ emb2_w,
    const int* __restrict__ ei, const int* __restrict__ z,
    const float* __restrict__ ls0_w, const float* __restrict__ ls1_w,
    const float* __restrict__ lt0_w, const float* __restrict__ lt1_w,
    const float* __restrict__ lt2_w,
    const float* __restrict__ dp1_w, const float* __restrict__ dp2_w,
    const float* __restrict__ dp3_w,
    float* __restrict__ U1, float* __restrict__ U2,
    int* __restrict__ cursor, int* __restrict__ order_pad,
    unsigned short* __restrict__ wb) {
    const int bx = blockIdx.x, tid = threadIdx.x;
    if (bx < 4096) {
        const int idx = bx * 4 + (tid >> 6);
        const int t = idx >> 7, h = idx & 127;
        const int lane = tid & 63;
        const float e0 = emb_w[t * 128 + lane];
        const float e1 = emb_w[t * 128 + 64 + lane];
        const float* row = emb2_w + h * 256;
        const float w0 = row[lane], w1 = row[64 + lane];
        const float w2 = row[128 + lane], w3 = row[192 + lane];
        float u1 = e0 * w0 + e1 * w1;
        float u2 = e0 * w2 + e1 * w3;
#pragma unroll
        for (int o = 1; o < 64; o <<= 1) {
            u1 += __shfl_xor(u1, o, 64);
            u2 += __shfl_xor(u2, o, 64);
        }
        if (lane == 0) {
            U1[t * 128 + h] = u1;
            U2[t * 128 + h] = u2;
        }
    } else if (bx < 4352) {
        const int e = (bx - 4096) * 256 + tid;
        const int src = ei[e];
        const int zd = z[ei[N_EDGE + e]];
        const int pos = atomicAdd(&cursor[src], 1);
        if (pos < 64) order_pad[(src << 6) + pos] = e | (zd << 16);
    } else {
        const int base = (bx - 4352) * 1024 + tid * 4;
        const float* src;
        int off;
        if (base < 32768)       { src = ls0_w; off = 0; }
        else if (base < 131072) { src = ls1_w; off = 32768; }
        else if (base < 147456) { src = lt0_w; off = 131072; }
        else if (base < 163840) { src = lt1_w; off = 147456; }
        else if (base < 180224) { src = lt2_w; off = 163840; }
        else if (base < 184320) { src = dp1_w; off = 180224; }
        else if (base < 188416) { src = dp2_w; off = 184320; }
        else                    { src = dp3_w; off = 188416; }
        const float4 v = *(const float4*)(src + (base - off));
        unsigned short* o = wb + base;
        o[0] = f2bf(v.x); o[1] = f2bf(v.y); o[2] = f2bf(v.z); o[3] = f2bf(v.w);
    }
}

// ---------------------------------------------------------------------------
// k_fused v2: 512 threads = two 4-wave TEAMS, 8 nodes/block, 512 blocks.
// Edge phase: team t handles nodes 4t..4t+3 (wall halves vs 256-thr).
// Tail: gates1 8 waves x 32 cols; gates2 6 waves x 64 cols; mix split
// team A planes 0-4 / team B planes 5-9 with LDS exchange of e2/tr partials.
// ---------------------------------------------------------------------------
__global__ __launch_bounds__(512) void k_fused(
    const int* __restrict__ z, const int* __restrict__ ecnt,
    const int* __restrict__ order_pad,
    const float* __restrict__ edge_vec,
    const float* __restrict__ U1, const float* __restrict__ U2,
    const float* __restrict__ emb2_b,
    const float* __restrict__ dp1_b, const float* __restrict__ dp2_b,
    const float* __restrict__ dp3_b,
    const unsigned short* __restrict__ wb,
    const float* __restrict__ init_g, const float* __restrict__ init_b,
    const float* __restrict__ ls0_b, const float* __restrict__ ls1_b,
    const float* __restrict__ outn_g, const float* __restrict__ outn_b,
    const float* __restrict__ lin_w, const float* __restrict__ lin_b,
    const float* __restrict__ ol1_w, const float* __restrict__ ol1_b,
    const float* __restrict__ ol2_w, const float* __restrict__ ol2_b,
    float* __restrict__ out) {
    const int tid = threadIdx.x;
    const int wave = tid >> 6, lane = tid & 63, lm = lane & 15, lq = lane >> 4;
    const int team = wave >> 2, tw = wave & 3;
    const int n0 = blockIdx.x * 8;
    const int ar = (lm < 8) ? lm : 7;

    // ---- manual LDS carve (38912 B), lifetime-based aliasing ----
    __shared__ alignas(16) char smem[38912];
    unsigned short (*accs)[8][136] = reinterpret_cast<unsigned short(*)[8][136]>(smem);          // 21760
    unsigned short (*nrms)[136]    = reinterpret_cast<unsigned short(*)[136]>(smem + 21760);     // 2176
    unsigned short (*h1)[264]      = reinterpret_cast<unsigned short(*)[264]>(smem + 23936);     // 8448
    unsigned short (*scal_s)[392]  = reinterpret_cast<unsigned short(*)[392]>(smem + 32384);     // 6272
    float (*redS)[4]               = reinterpret_cast<float(*)[4]>(smem + 38656);                // 128
    float (*redQ)[4]               = reinterpret_cast<float(*)[4]>(smem + 38784);                // 128
    float (*xs)[392]               = reinterpret_cast<float(*)[392]>(smem);                      // alias accs (dead after mix)
    float (*ss)[132]               = reinterpret_cast<float(*)[132]>(smem + 23936);              // alias h1
    float* exch                    = reinterpret_cast<float*>(smem + 23936);                     // alias h1 (mix exchange, 8 KB)

    // ======================= EDGE PHASE =======================
    const unsigned short* dpw = wb + WB_DP;
    bf16x8 bfr[3][2];
    float bhc[2], bk1[2], bk2[2], bk3[2];
    int cols[2];
#pragma unroll
    for (int t = 0; t < 2; t++) {
        const int col = tw * 32 + t * 16 + lm;
        cols[t] = col;
        bhc[t] = emb2_b[col];
        bk1[t] = dp1_b[col]; bk2[t] = dp2_b[col]; bk3[t] = dp3_b[col];
#pragma unroll
        for (int k = 0; k < 3; k++)
            bfr[k][t] = *(const bf16x8*)(dpw + k * 4096 + col * 32 + lq * 8);
    }

    const float m0 = 0.011108996538242306f;
    const float dm = (1.0f - m0) * (1.0f / 31.0f);
    const float tb = 0.0625f * (1.0f - m0);
    const float beta = 1.0f / (tb * tb);
    const float mean0 = m0 + (float)(lq * 8) * dm;

    float tnA[4], tnB[4];

    for (int nn2 = 0; nn2 < 4; nn2++) {
        const int nn = team * 4 + nn2;
        const int n = n0 + nn;
        const int En = min(ecnt[n], 64);
        const int beg = n << 6;
        const int zoff = z[n] << 7;
        const float u1c0 = U1[zoff + cols[0]];
        const float u1c1 = U1[zoff + cols[1]];

        float part[10][2];
#pragma unroll
        for (int p = 0; p < 10; p++) { part[p][0] = 0.f; part[p][1] = 0.f; }

        for (int mi = 0; mi < En; mi += 16) {
            const int wrd = order_pad[beg + min(mi + lm, En - 1)];
            const int e = wrd & 0xFFFF;
            const int u2o = (wrd >> 16) << 7;
            const float evx = edge_vec[3 * e + 0];
            const float evy = edge_vec[3 * e + 1];
            const float evz = edge_vec[3 * e + 2];
            const float d = sqrtf(evx * evx + evy * evy + evz * evz);
            const float inv = 1.0f / d;
            const float cut = (d < 4.5f) ? 0.5f * (__cosf(0.6981317007977318f * d) + 1.0f) : 0.0f;
            const float vx = evx * inv, vy = evy * inv, vz = evz * inv;
            const float expd = __expf(-1.1111111111111112f * d);

            union { bf16x8 v; unsigned short s[8]; } uf;
#pragma unroll
            for (int j = 0; j < 8; j++) {
                const float df = expd - (mean0 + (float)j * dm);
                uf.s[j] = f2bf(cut * __expf(-beta * df * df));
            }
            const bf16x8 af = uf.v;

            f32x4 c[3][2];
#pragma unroll
            for (int k = 0; k < 3; k++)
#pragma unroll
                for (int t = 0; t < 2; t++)
                    c[k][t] = __builtin_amdgcn_mfma_f32_16x16x32_bf16(
                        af, bfr[k][t], (f32x4){0.f, 0.f, 0.f, 0.f}, 0, 0, 0);

#pragma unroll
            for (int r = 0; r < 4; r++) {
                const int er = mi + lq * 4 + r;
                const bool valid = er < En;
                const int sl = (lane & 48) | (lq * 4 + r);
                const float gvx = __shfl(vx, sl, 64);
                const float gvy = __shfl(vy, sl, 64);
                const float gvz = __shfl(vz, sl, 64);
                const float gct = __shfl(cut, sl, 64);
                const int   go  = __shfl(u2o, sl, 64);
#pragma unroll
                for (int t = 0; t < 2; t++) {
                    const float u2v = U2[go + cols[t]];
                    const float u1h = (t == 0) ? u1c0 : u1c1;
                    const float cc = valid ? gct * (u1h + u2v + bhc[t]) : 0.f;
                    const float w1 = (c[0][t][r] + bk1[t]) * cc;
                    const float w2 = (c[1][t][r] + bk2[t]) * cc;
                    const float w3 = (c[2][t][r] + bk3[t]) * cc;
                    part[0][t] += w1;
                    part[1][t] += w2 * gvx; part[2][t] += w2 * gvy; part[3][t] += w2 * gvz;
                    const float tx = w3 * gvx, ty = w3 * gvy;
                    part[4][t] += tx * gvx; part[5][t] += tx * gvy; part[6][t] += tx * gvz;
                    part[7][t] += ty * gvy; part[8][t] += ty * gvz; part[9][t] += w3 * gvz * gvz;
                }
            }
        }

#pragma unroll
        for (int p = 0; p < 10; p++)
#pragma unroll
            for (int t = 0; t < 2; t++) {
                float v = part[p][t];
                v += __shfl_xor(v, 16, 64);
                v += __shfl_xor(v, 32, 64);
                part[p][t] = v;
            }
        if (lq == 0) {
#pragma unroll
            for (int p = 0; p < 10; p++)
#pragma unroll
                for (int t = 0; t < 2; t++)
                    accs[p][nn][cols[t]] = f2bf(part[p][t]);
        }

        float tn[2];
#pragma unroll
        for (int t = 0; t < 2; t++) {
            const float aI = part[0][t];
            const float axv = part[1][t], ayv = part[2][t], azv = part[3][t];
            const float mxx = part[4][t], mxy = part[5][t], mxz = part[6][t];
            const float myy = part[7][t], myz = part[8][t], mzz = part[9][t];
            const float tr3 = (mxx + myy + mzz) * (1.0f / 3.0f);
            const float t00 = aI + mxx - tr3;
            const float t11 = aI + myy - tr3;
            const float t22 = aI + mzz - tr3;
            tn[t] = t00 * t00 + t11 * t11 + t22 * t22 +
                    2.0f * (mxy * mxy + azv * azv + mxz * mxz + ayv * ayv + myz * myz + axv * axv);
        }
        tnA[nn2] = tn[0];
        tnB[nn2] = tn[1];

        float s = (lq == 0) ? (tn[0] + tn[1]) : 0.f;
        s += __shfl_xor(s, 1, 64);
        s += __shfl_xor(s, 2, 64);
        s += __shfl_xor(s, 4, 64);
        s += __shfl_xor(s, 8, 64);
        if (lane == 0) redS[nn][tw] = s;
    }
    __syncthreads();

    {
        float dvA[4], dvB[4];
#pragma unroll
        for (int nn2 = 0; nn2 < 4; nn2++) {
            const int nn = team * 4 + nn2;
            const float mu = (redS[nn][0] + redS[nn][1] + redS[nn][2] + redS[nn][3]) * (1.0f / 128.0f);
            dvA[nn2] = tnA[nn2] - mu;
            dvB[nn2] = tnB[nn2] - mu;
            float q = (lq == 0) ? (dvA[nn2] * dvA[nn2] + dvB[nn2] * dvB[nn2]) : 0.f;
            q += __shfl_xor(q, 1, 64);
            q += __shfl_xor(q, 2, 64);
            q += __shfl_xor(q, 4, 64);
            q += __shfl_xor(q, 8, 64);
            if (lane == 0) redQ[nn][tw] = q;
        }
        __syncthreads();
        if (lq == 0) {
            const float g0 = init_g[cols[0]], g1 = init_g[cols[1]];
            const float b0 = init_b[cols[0]], b1 = init_b[cols[1]];
#pragma unroll
            for (int nn2 = 0; nn2 < 4; nn2++) {
                const int nn = team * 4 + nn2;
                const float var = (redQ[nn][0] + redQ[nn][1] + redQ[nn][2] + redQ[nn][3]) * (1.0f / 128.0f);
                const float rs = rsqrtf(var + 1e-5f);
                nrms[nn][cols[0]] = f2bf(dvA[nn2] * rs * g0 + b0);
                nrms[nn][cols[1]] = f2bf(dvB[nn2] * rs * g1 + b1);
            }
        }
    }
    __syncthreads();

    // ======================= TAIL PHASE =======================
    // ---- gates GEMM1: 8 waves x 32 cols (N=256)
    {
        f32x4 acc[2];
        acc[0] = (f32x4){0.f, 0.f, 0.f, 0.f};
        acc[1] = (f32x4){0.f, 0.f, 0.f, 0.f};
        const int cbase = wave * 32;
#pragma unroll
        for (int kc = 0; kc < 128; kc += 32) {
            const bf16x8 af = *(const bf16x8*)(&nrms[ar][kc + lq * 8]);
#pragma unroll
            for (int sn = 0; sn < 2; sn++) {
                const bf16x8 b = *(const bf16x8*)(wb + (size_t)(cbase + sn * 16 + lm) * 128 + kc + lq * 8);
                acc[sn] = __builtin_amdgcn_mfma_f32_16x16x32_bf16(af, b, acc[sn], 0, 0, 0);
            }
        }
#pragma unroll
        for (int sn = 0; sn < 2; sn++) {
            const int col = cbase + sn * 16 + lm;
            const float bv = ls0_b[col];
#pragma unroll
            for (int r = 0; r < 4; r++)
                h1[lq * 4 + r][col] = f2bf(silu(acc[sn][r] + bv));
        }
    }
    __syncthreads();
    // ---- gates GEMM2: waves 0-5 x 64 cols (N=384), K=256
    if (wave < 6) {
        f32x4 acc[4];
#pragma unroll
        for (int j = 0; j < 4; j++) acc[j] = (f32x4){0.f, 0.f, 0.f, 0.f};
        const int cbase = wave * 64;
        const unsigned short* ls1p = wb + WB_LS1;
#pragma unroll 2
        for (int kc = 0; kc < 256; kc += 32) {
            const bf16x8 af = *(const bf16x8*)(&h1[lm][kc + lq * 8]);
#pragma unroll
            for (int sn = 0; sn < 4; sn++) {
                const bf16x8 b = *(const bf16x8*)(ls1p + (size_t)(cbase + sn * 16 + lm) * 256 + kc + lq * 8);
                acc[sn] = __builtin_amdgcn_mfma_f32_16x16x32_bf16(af, b, acc[sn], 0, 0, 0);
            }
        }
#pragma unroll
        for (int sn = 0; sn < 4; sn++) {
            const int col = cbase + sn * 16 + lm;
            const float bv = ls1_b[col];
#pragma unroll
            for (int r = 0; r < 4; r++) {
                const int node = lq * 4 + r;
                if (node < 8) scal_s[node][col] = f2bf(silu(acc[sn][r] + bv));
            }
        }
    }
    __syncthreads();

    // ---- mix: team A planes 0-4, team B planes 5-9; A from LDS accs
    f32x4 e0[2], e1[2], e2[2], trv[2];
#pragma unroll
    for (int sn = 0; sn < 2; sn++) {
        e0[sn] = (f32x4){0.f, 0.f, 0.f, 0.f};
        e1[sn] = (f32x4){0.f, 0.f, 0.f, 0.f};
        e2[sn] = (f32x4){0.f, 0.f, 0.f, 0.f};
        trv[sn] = (f32x4){0.f, 0.f, 0.f, 0.f};
    }
#pragma unroll
    for (int pp = 0; pp < 5; pp++) {
        const int p = team * 5 + pp;
        const unsigned short* B = wb + (p == 0 ? WB_LT0 : (p < 4 ? WB_LT1 : WB_LT2));
        f32x4 c[2];
        c[0] = (f32x4){0.f, 0.f, 0.f, 0.f};
        c[1] = (f32x4){0.f, 0.f, 0.f, 0.f};
#pragma unroll
        for (int kc = 0; kc < 128; kc += 32) {
            const bf16x8 af = *(const bf16x8*)(&accs[p][ar][kc + lq * 8]);
#pragma unroll
            for (int sn = 0; sn < 2; sn++) {
                const bf16x8 b = *(const bf16x8*)(B + (size_t)(tw * 32 + sn * 16 + lm) * 128 + kc + lq * 8);
                c[sn] = __builtin_amdgcn_mfma_f32_16x16x32_bf16(af, b, c[sn], 0, 0, 0);
            }
        }
#pragma unroll
        for (int sn = 0; sn < 2; sn++) {
            if (p == 0)      e0[sn] += c[sn] * c[sn];
            else if (p < 4)  e1[sn] += c[sn] * c[sn];
            else if (p == 4 || p == 7 || p == 9) { e2[sn] += c[sn] * c[sn]; trv[sn] += c[sn]; }
            else             e2[sn] += 2.0f * c[sn] * c[sn];
        }
    }
    __syncthreads();   // accs dead; h1 (exch) free

    // ---- cross-team exchange of e2/tr partials (team B -> LDS)
    if (team == 1 && lq < 2) {
#pragma unroll
        for (int sn = 0; sn < 2; sn++)
#pragma unroll
            for (int r = 0; r < 4; r++) {
                const int node = lq * 4 + r;
                const int idx = ((tw * 2 + sn) * 8 + node) * 16 + lm;
                exch[idx] = e2[sn][r];
                exch[1024 + idx] = trv[sn][r];
            }
    }
    __syncthreads();

    // ---- combine + gate (team A; xs aliases accs)
    if (team == 0 && lq < 2) {
#pragma unroll
        for (int sn = 0; sn < 2; sn++) {
#pragma unroll
            for (int r = 0; r < 4; r++) {
                const int node = lq * 4 + r;
                const int g = tw * 32 + sn * 16 + lm;
                const int idx = ((tw * 2 + sn) * 8 + node) * 16 + lm;
                const float e2t = e2[sn][r] + exch[idx];
                const float trt = trv[sn][r] + exch[1024 + idx];
                const float s0 = bf2f(scal_s[node][3 * g + 0]);
                const float s1 = bf2f(scal_s[node][3 * g + 1]);
                const float s2 = bf2f(scal_s[node][3 * g + 2]);
                xs[node][g]       = 3.0f * e0[sn][r] * s0 * s0;
                xs[node][128 + g] = 2.0f * e1[sn][r] * s1 * s1;
                xs[node][256 + g] = (e2t - trt * trt * (1.0f / 3.0f)) * s2 * s2;
            }
        }
    }
    __syncthreads();

    // ---- LN(384): wave w normalizes node w
    {
        const int node = wave;
        float v[6];
        float s = 0.f;
#pragma unroll
        for (int j = 0; j < 6; j++) { v[j] = xs[node][lane + 64 * j]; s += v[j]; }
#pragma unroll
        for (int o = 1; o < 64; o <<= 1) s += __shfl_xor(s, o, 64);
        const float mu = s * (1.0f / 384.0f);
        float q = 0.f;
#pragma unroll
        for (int j = 0; j < 6; j++) { v[j] -= mu; q += v[j] * v[j]; }
#pragma unroll
        for (int o = 1; o < 64; o <<= 1) q += __shfl_xor(q, o, 64);
        const float rs = rsqrtf(q * (1.0f / 384.0f) + 1e-5f);
#pragma unroll
        for (int j = 0; j < 6; j++) {
            const int col = lane + 64 * j;
            xs[node][col] = v[j] * rs * outn_g[col] + outn_b[col];
        }
    }
    __syncthreads();

    // ---- lin: 4 groups of 128 threads x 2 nodes (ss aliases h1/exch, dead)
    {
        const int j = tid & 127, grp = tid >> 7;
        float a2[2];
        const float lb = lin_b[j];
        a2[0] = lb; a2[1] = lb;
        const float4* wr = (const float4*)(lin_w + j * 384);
#pragma unroll 2
        for (int k4 = 0; k4 < 96; k4++) {
            const float4 w4 = wr[k4];
#pragma unroll
            for (int i = 0; i < 2; i++) {
                const float4 xv = *(const float4*)&xs[grp * 2 + i][k4 * 4];
                a2[i] += w4.x * xv.x + w4.y * xv.y + w4.z * xv.z + w4.w * xv.w;
            }
        }
        __syncthreads();   // exch/h1 fully dead before ss writes
#pragma unroll
        for (int i = 0; i < 2; i++) ss[grp * 2 + i][j] = silu(a2[i]);
    }
    __syncthreads();

    // ---- ol1 + ol2: 8 quads, one node each
    {
        const int o = tid & 63, q = tid >> 6;
        float a = ol1_b[o];
        const float4* o4 = (const float4*)(ol1_w + o * 128);
#pragma unroll 4
        for (int k4 = 0; k4 < 32; k4++) {
            const float4 w4 = o4[k4];
            const float4 sv = *(const float4*)&ss[q][k4 * 4];
            a += w4.x * sv.x + w4.y * sv.y + w4.z * sv.z + w4.w * sv.w;
        }
        float v = silu(a) * ol2_w[o];
        for (int s = 32; s > 0; s >>= 1) v += __shfl_down(v, s, 64);
        if (o == 0) out[n0 + q] = v + ol2_b[0];
    }
}

// ---------------------------------------------------------------------------
extern "C" void kernel_launch(void* const* d_in, const int* in_sizes, int n_in,
                              void* d_out, int out_size, void* d_ws, size_t ws_size,
                              hipStream_t stream) {
    (void)in_sizes; (void)n_in; (void)out_size; (void)ws_size;
    const float* edge_vec = (const float*)d_in[0];
    const float* emb_w   = (const float*)d_in[1];
    const float* emb2_w  = (const float*)d_in[2];
    const float* emb2_b  = (const float*)d_in[3];
    const float* dp1_w   = (const float*)d_in[4];
    const float* dp1_b   = (const float*)d_in[5];
    const float* dp2_w   = (const float*)d_in[6];
    const float* dp2_b   = (const float*)d_in[7];
    const float* dp3_w   = (const float*)d_in[8];
    const float* dp3_b   = (const float*)d_in[9];
    const float* lt0_w   = (const float*)d_in[10];
    const float* lt1_w   = (const float*)d_in[11];
    const float* lt2_w   = (const float*)d_in[12];
    const float* ls0_w   = (const float*)d_in[13];
    const float* ls0_b   = (const float*)d_in[14];
    const float* ls1_w   = (const float*)d_in[15];
    const float* ls1_b   = (const float*)d_in[16];
    const float* init_g  = (const float*)d_in[17];
    const float* init_b  = (const float*)d_in[18];
    const float* lin_w   = (const float*)d_in[19];
    const float* lin_b   = (const float*)d_in[20];
    const float* outn_g  = (const float*)d_in[21];
    const float* outn_b  = (const float*)d_in[22];
    const float* ol1_w   = (const float*)d_in[23];
    const float* ol1_b   = (const float*)d_in[24];
    const float* ol2_w   = (const float*)d_in[25];
    const float* ol2_b   = (const float*)d_in[26];
    const int* z  = (const int*)d_in[27];
    const int* ei = (const int*)d_in[28];
    float* out = (float*)d_out;

    char* w = (char*)d_ws;
    int*            cursor    = (int*)(w);                      // -> 16384
    unsigned short* wb        = (unsigned short*)(w + 16384);   // -> 401408
    float*          U1        = (float*)(w + 401408);           // -> 466944
    float*          U2        = (float*)(w + 466944);           // -> 532480
    int*            order_pad = (int*)(w + 532480);             // -> 1581056

    hipMemsetAsync(w, 0, 16384, stream);  // cursor
    k_setup<<<dim3(4540), dim3(256), 0, stream>>>(emb_w, emb2_w, ei, z,
                                                  ls0_w, ls1_w, lt0_w, lt1_w, lt2_w,
                                                  dp1_w, dp2_w, dp3_w,
                                                  U1, U2, cursor, order_pad, wb);
    k_fused<<<dim3(512), dim3(512), 0, stream>>>(z, cursor, order_pad, edge_vec,
                                                 U1, U2, emb2_b, dp1_b, dp2_b, dp3_b, wb,
                                                 init_g, init_b, ls0_b, ls1_b,
                                                 outn_g, outn_b, lin_w, lin_b,
                                                 ol1_w, ol1_b, ol2_w, ol2_b, out);
}

// Round 16
// 210.063 us; speedup vs baseline: 1.2243x; 1.2243x over previous
//
#include <hip/hip_runtime.h>
#include <math.h>

#define NH_TOT 524288   // 4096*128
#define N_ATOM 4096
#define N_EDGE 65536

typedef __attribute__((ext_vector_type(8))) short bf16x8;
typedef __attribute__((ext_vector_type(4))) float f32x4;

__device__ __forceinline__ unsigned short f2bf(float f) {
    unsigned u = __builtin_bit_cast(unsigned, f);
    unsigned r = (u + 0x7fffu + ((u >> 16) & 1u)) >> 16;
    return (unsigned short)r;
}
__device__ __forceinline__ float bf2f(unsigned short s) {
    unsigned u = ((unsigned)s) << 16;
    return __builtin_bit_cast(float, u);
}
__device__ __forceinline__ float silu(float v) { return v / (1.0f + __expf(-v)); }

// wb layout (bf16 elements):
// ls0@0(32768), ls1@32768(98304), lt0@131072(16384), lt1@147456(16384),
// lt2@163840(16384), dp1@180224(4096), dp2@184320(4096), dp3@188416(4096)
#define WB_LS1 32768
#define WB_LT0 131072
#define WB_LT1 147456
#define WB_LT2 163840
#define WB_DP  180224

// ---------------------------------------------------------------------------
// Setup: [0,4096) U1/U2 (one wave per (t,h), coalesced); [4096,4352) edge
// scatter into padded per-node buckets, packing e | z_dst<<16; [4352,4540)
// weight bf16 conversion.
// ---------------------------------------------------------------------------
__global__ __launch_bounds__(256) void k_setup(
    const float* __restrict__ emb_w, const float* __restrict__ emb2_w,
    const int* __restrict__ ei, const int* __restrict__ z,
    const float* __restrict__ ls0_w, const float* __restrict__ ls1_w,
    const float* __restrict__ lt0_w, const float* __restrict__ lt1_w,
    const float* __restrict__ lt2_w,
    const float* __restrict__ dp1_w, const float* __restrict__ dp2_w,
    const float* __restrict__ dp3_w,
    float* __restrict__ U1, float* __restrict__ U2,
    int* __restrict__ cursor, int* __restrict__ order_pad,
    unsigned short* __restrict__ wb) {
    const int bx = blockIdx.x, tid = threadIdx.x;
    if (bx < 4096) {
        const int idx = bx * 4 + (tid >> 6);
        const int t = idx >> 7, h = idx & 127;
        const int lane = tid & 63;
        const float e0 = emb_w[t * 128 + lane];
        const float e1 = emb_w[t * 128 + 64 + lane];
        const float* row = emb2_w + h * 256;
        const float w0 = row[lane], w1 = row[64 + lane];
        const float w2 = row[128 + lane], w3 = row[192 + lane];
        float u1 = e0 * w0 + e1 * w1;
        float u2 = e0 * w2 + e1 * w3;
#pragma unroll
        for (int o = 1; o < 64; o <<= 1) {
            u1 += __shfl_xor(u1, o, 64);
            u2 += __shfl_xor(u2, o, 64);
        }
        if (lane == 0) {
            U1[t * 128 + h] = u1;
            U2[t * 128 + h] = u2;
        }
    } else if (bx < 4352) {
        const int e = (bx - 4096) * 256 + tid;
        const int src = ei[e];
        const int zd = z[ei[N_EDGE + e]];
        const int pos = atomicAdd(&cursor[src], 1);
        if (pos < 64) order_pad[(src << 6) + pos] = e | (zd << 16);
    } else {
        const int base = (bx - 4352) * 1024 + tid * 4;
        const float* src;
        int off;
        if (base < 32768)       { src = ls0_w; off = 0; }
        else if (base < 131072) { src = ls1_w; off = 32768; }
        else if (base < 147456) { src = lt0_w; off = 131072; }
        else if (base < 163840) { src = lt1_w; off = 147456; }
        else if (base < 180224) { src = lt2_w; off = 163840; }
        else if (base < 184320) { src = dp1_w; off = 180224; }
        else if (base < 188416) { src = dp2_w; off = 184320; }
        else                    { src = dp3_w; off = 188416; }
        const float4 v = *(const float4*)(src + (base - off));
        unsigned short* o = wb + base;
        o[0] = f2bf(v.x); o[1] = f2bf(v.y); o[2] = f2bf(v.z); o[3] = f2bf(v.w);
    }
}

// ---------------------------------------------------------------------------
// k_fused (round-14 structure + RBF ladder recurrence): edge accumulation
// (MFMA, in-kernel rbf with 4 transcendentals/tile via f_{j+1}=f_j*G, G*=rho)
// + tensor_norm + LN(init) + gates + 10-plane mix + combine + LN(384)
// + lin + ol1 + ol2. Block = 8 nodes, 256 threads, 512 blocks. LDS 38.9 KB.
// ---------------------------------------------------------------------------
__global__ __launch_bounds__(256) void k_fused(
    const int* __restrict__ z, const int* __restrict__ ecnt,
    const int* __restrict__ order_pad,
    const float* __restrict__ edge_vec,
    const float* __restrict__ U1, const float* __restrict__ U2,
    const float* __restrict__ emb2_b,
    const float* __restrict__ dp1_b, const float* __restrict__ dp2_b,
    const float* __restrict__ dp3_b,
    const unsigned short* __restrict__ wb,
    const float* __restrict__ init_g, const float* __restrict__ init_b,
    const float* __restrict__ ls0_b, const float* __restrict__ ls1_b,
    const float* __restrict__ outn_g, const float* __restrict__ outn_b,
    const float* __restrict__ lin_w, const float* __restrict__ lin_b,
    const float* __restrict__ ol1_w, const float* __restrict__ ol1_b,
    const float* __restrict__ ol2_w, const float* __restrict__ ol2_b,
    float* __restrict__ out) {
    const int tid = threadIdx.x;
    const int wave = tid >> 6, lane = tid & 63, lm = lane & 15, lq = lane >> 4;
    const int n0 = blockIdx.x * 8;
    const int ar = (lm < 8) ? lm : 7;

    // ---- manual LDS carve (38912 B total), lifetime-based aliasing ----
    __shared__ alignas(16) char smem[38912];
    unsigned short (*accs)[8][136] = reinterpret_cast<unsigned short(*)[8][136]>(smem);          // 21760
    unsigned short (*nrms)[136]    = reinterpret_cast<unsigned short(*)[136]>(smem + 21760);     // 2176
    unsigned short (*h1)[264]      = reinterpret_cast<unsigned short(*)[264]>(smem + 23936);     // 8448
    unsigned short (*scal_s)[392]  = reinterpret_cast<unsigned short(*)[392]>(smem + 32384);     // 6272
    float (*redS)[4]               = reinterpret_cast<float(*)[4]>(smem + 38656);                // 128
    float (*redQ)[4]               = reinterpret_cast<float(*)[4]>(smem + 38784);                // 128
    float (*xs)[392]               = reinterpret_cast<float(*)[392]>(smem);                      // alias accs (dead after mix)
    float (*ss)[132]               = reinterpret_cast<float(*)[132]>(smem + 23936);              // alias h1 (dead after gates2)

    // ======================= EDGE PHASE =======================
    const unsigned short* dpw = wb + WB_DP;
    bf16x8 bfr[3][2];
    float bhc[2], bk1[2], bk2[2], bk3[2];
    int cols[2];
#pragma unroll
    for (int t = 0; t < 2; t++) {
        const int col = wave * 32 + t * 16 + lm;
        cols[t] = col;
        bhc[t] = emb2_b[col];
        bk1[t] = dp1_b[col]; bk2[t] = dp2_b[col]; bk3[t] = dp3_b[col];
#pragma unroll
        for (int k = 0; k < 3; k++)
            bfr[k][t] = *(const bf16x8*)(dpw + k * 4096 + col * 32 + lq * 8);
    }

    const float m0 = 0.011108996538242306f;
    const float dm = (1.0f - m0) * (1.0f / 31.0f);
    const float tb = 0.0625f * (1.0f - m0);
    const float beta = 1.0f / (tb * tb);
    const float mean0 = m0 + (float)(lq * 8) * dm;   // lane's first RBF mean
    // RBF ladder constants: f_{j+1} = f_j * E * K0 * rho^j,  E = exp(2*beta*dm*x)
    const float rho = __expf(-2.0f * beta * dm * dm);
    const float K0c = __expf(-beta * dm * (2.0f * mean0 + dm));
    const float twoBD = 2.0f * beta * dm;

    float tnA[8], tnB[8];

    for (int nn = 0; nn < 8; nn++) {
        const int n = n0 + nn;
        const int En = min(ecnt[n], 64);
        const int beg = n << 6;
        const int zoff = z[n] << 7;
        const float u1c0 = U1[zoff + cols[0]];
        const float u1c1 = U1[zoff + cols[1]];

        float part[10][2];
#pragma unroll
        for (int p = 0; p < 10; p++) { part[p][0] = 0.f; part[p][1] = 0.f; }

        for (int mi = 0; mi < En; mi += 16) {
            const int wrd = order_pad[beg + min(mi + lm, En - 1)];
            const int e = wrd & 0xFFFF;
            const int u2o = (wrd >> 16) << 7;
            const float evx = edge_vec[3 * e + 0];
            const float evy = edge_vec[3 * e + 1];
            const float evz = edge_vec[3 * e + 2];
            const float d = sqrtf(evx * evx + evy * evy + evz * evz);
            const float inv = 1.0f / d;
            const float cut = (d < 4.5f) ? 0.5f * (__cosf(0.6981317007977318f * d) + 1.0f) : 0.0f;
            const float vx = evx * inv, vy = evy * inv, vz = evz * inv;
            const float x = __expf(-1.1111111111111112f * d);

            // RBF ladder: 4 transcendentals total (x, cut's cos, f0, E)
            union { bf16x8 v; unsigned short s[8]; } uf;
            const float d0f = x - mean0;
            float f = cut * __expf(-beta * d0f * d0f);
            float G = __expf(twoBD * x) * K0c;
            uf.s[0] = f2bf(f);
#pragma unroll
            for (int j = 1; j < 8; j++) {
                f *= G;
                G *= rho;
                uf.s[j] = f2bf(f);
            }
            const bf16x8 af = uf.v;

            f32x4 c[3][2];
#pragma unroll
            for (int k = 0; k < 3; k++)
#pragma unroll
                for (int t = 0; t < 2; t++)
                    c[k][t] = __builtin_amdgcn_mfma_f32_16x16x32_bf16(
                        af, bfr[k][t], (f32x4){0.f, 0.f, 0.f, 0.f}, 0, 0, 0);

#pragma unroll
            for (int r = 0; r < 4; r++) {
                const int er = mi + lq * 4 + r;
                const bool valid = er < En;
                const int sl = (lane & 48) | (lq * 4 + r);
                const float gvx = __shfl(vx, sl, 64);
                const float gvy = __shfl(vy, sl, 64);
                const float gvz = __shfl(vz, sl, 64);
                const float gct = __shfl(cut, sl, 64);
                const int   go  = __shfl(u2o, sl, 64);
#pragma unroll
                for (int t = 0; t < 2; t++) {
                    const float u2v = U2[go + cols[t]];
                    const float u1h = (t == 0) ? u1c0 : u1c1;
                    const float cc = valid ? gct * (u1h + u2v + bhc[t]) : 0.f;
                    const float w1 = (c[0][t][r] + bk1[t]) * cc;
                    const float w2 = (c[1][t][r] + bk2[t]) * cc;
                    const float w3 = (c[2][t][r] + bk3[t]) * cc;
                    part[0][t] += w1;
                    part[1][t] += w2 * gvx; part[2][t] += w2 * gvy; part[3][t] += w2 * gvz;
                    const float tx = w3 * gvx, ty = w3 * gvy;
                    part[4][t] += tx * gvx; part[5][t] += tx * gvy; part[6][t] += tx * gvz;
                    part[7][t] += ty * gvy; part[8][t] += ty * gvz; part[9][t] += w3 * gvz * gvz;
                }
            }
        }

#pragma unroll
        for (int p = 0; p < 10; p++)
#pragma unroll
            for (int t = 0; t < 2; t++) {
                float v = part[p][t];
                v += __shfl_xor(v, 16, 64);
                v += __shfl_xor(v, 32, 64);
                part[p][t] = v;
            }
        if (lq == 0) {
#pragma unroll
            for (int p = 0; p < 10; p++)
#pragma unroll
                for (int t = 0; t < 2; t++)
                    accs[p][nn][cols[t]] = f2bf(part[p][t]);
        }

        float tn[2];
#pragma unroll
        for (int t = 0; t < 2; t++) {
            const float aI = part[0][t];
            const float axv = part[1][t], ayv = part[2][t], azv = part[3][t];
            const float mxx = part[4][t], mxy = part[5][t], mxz = part[6][t];
            const float myy = part[7][t], myz = part[8][t], mzz = part[9][t];
            const float tr3 = (mxx + myy + mzz) * (1.0f / 3.0f);
            const float t00 = aI + mxx - tr3;
            const float t11 = aI + myy - tr3;
            const float t22 = aI + mzz - tr3;
            tn[t] = t00 * t00 + t11 * t11 + t22 * t22 +
                    2.0f * (mxy * mxy + azv * azv + mxz * mxz + ayv * ayv + myz * myz + axv * axv);
        }
        tnA[nn] = tn[0];
        tnB[nn] = tn[1];

        float s = (lq == 0) ? (tn[0] + tn[1]) : 0.f;
        s += __shfl_xor(s, 1, 64);
        s += __shfl_xor(s, 2, 64);
        s += __shfl_xor(s, 4, 64);
        s += __shfl_xor(s, 8, 64);
        if (lane == 0) redS[nn][wave] = s;
    }
    __syncthreads();

    {
        float dvA[8], dvB[8];
#pragma unroll
        for (int nn = 0; nn < 8; nn++) {
            const float mu = (redS[nn][0] + redS[nn][1] + redS[nn][2] + redS[nn][3]) * (1.0f / 128.0f);
            dvA[nn] = tnA[nn] - mu;
            dvB[nn] = tnB[nn] - mu;
            float q = (lq == 0) ? (dvA[nn] * dvA[nn] + dvB[nn] * dvB[nn]) : 0.f;
            q += __shfl_xor(q, 1, 64);
            q += __shfl_xor(q, 2, 64);
            q += __shfl_xor(q, 4, 64);
            q += __shfl_xor(q, 8, 64);
            if (lane == 0) redQ[nn][wave] = q;
        }
        __syncthreads();
        if (lq == 0) {
            const float g0 = init_g[cols[0]], g1 = init_g[cols[1]];
            const float b0 = init_b[cols[0]], b1 = init_b[cols[1]];
#pragma unroll
            for (int nn = 0; nn < 8; nn++) {
                const float var = (redQ[nn][0] + redQ[nn][1] + redQ[nn][2] + redQ[nn][3]) * (1.0f / 128.0f);
                const float rs = rsqrtf(var + 1e-5f);
                nrms[nn][cols[0]] = f2bf(dvA[nn] * rs * g0 + b0);
                nrms[nn][cols[1]] = f2bf(dvB[nn] * rs * g1 + b1);
            }
        }
    }
    __syncthreads();

    // ======================= TAIL PHASE =======================
    // ---- gates GEMM1
    {
        f32x4 acc[4];
#pragma unroll
        for (int j = 0; j < 4; j++) acc[j] = (f32x4){0.f, 0.f, 0.f, 0.f};
        const int cbase = wave * 64;
#pragma unroll
        for (int kc = 0; kc < 128; kc += 32) {
            const bf16x8 af = *(const bf16x8*)(&nrms[ar][kc + lq * 8]);
#pragma unroll
            for (int sn = 0; sn < 4; sn++) {
                const bf16x8 b = *(const bf16x8*)(wb + (size_t)(cbase + sn * 16 + lm) * 128 + kc + lq * 8);
                acc[sn] = __builtin_amdgcn_mfma_f32_16x16x32_bf16(af, b, acc[sn], 0, 0, 0);
            }
        }
#pragma unroll
        for (int sn = 0; sn < 4; sn++) {
            const int col = cbase + sn * 16 + lm;
            const float bv = ls0_b[col];
#pragma unroll
            for (int r = 0; r < 4; r++)
                h1[lq * 4 + r][col] = f2bf(silu(acc[sn][r] + bv));
        }
    }
    __syncthreads();
    // ---- gates GEMM2 (scal stored bf16)
    {
        f32x4 acc[6];
#pragma unroll
        for (int j = 0; j < 6; j++) acc[j] = (f32x4){0.f, 0.f, 0.f, 0.f};
        const int cbase = wave * 96;
        const unsigned short* ls1p = wb + WB_LS1;
#pragma unroll 2
        for (int kc = 0; kc < 256; kc += 32) {
            const bf16x8 af = *(const bf16x8*)(&h1[lm][kc + lq * 8]);
#pragma unroll
            for (int sn = 0; sn < 6; sn++) {
                const bf16x8 b = *(const bf16x8*)(ls1p + (size_t)(cbase + sn * 16 + lm) * 256 + kc + lq * 8);
                acc[sn] = __builtin_amdgcn_mfma_f32_16x16x32_bf16(af, b, acc[sn], 0, 0, 0);
            }
        }
#pragma unroll
        for (int sn = 0; sn < 6; sn++) {
            const int col = cbase + sn * 16 + lm;
            const float bv = ls1_b[col];
#pragma unroll
            for (int r = 0; r < 4; r++) {
                const int node = lq * 4 + r;
                if (node < 8) scal_s[node][col] = f2bf(silu(acc[sn][r] + bv));
            }
        }
    }
    __syncthreads();

    // ---- mix: 10 plane GEMMs, A from LDS accs
    f32x4 e0[2], e1[2], e2[2], trv[2];
#pragma unroll
    for (int sn = 0; sn < 2; sn++) {
        e0[sn] = (f32x4){0.f, 0.f, 0.f, 0.f};
        e1[sn] = (f32x4){0.f, 0.f, 0.f, 0.f};
        e2[sn] = (f32x4){0.f, 0.f, 0.f, 0.f};
        trv[sn] = (f32x4){0.f, 0.f, 0.f, 0.f};
    }
#pragma unroll
    for (int p = 0; p < 10; p++) {
        const unsigned short* B = wb + (p == 0 ? WB_LT0 : (p < 4 ? WB_LT1 : WB_LT2));
        f32x4 c[2];
        c[0] = (f32x4){0.f, 0.f, 0.f, 0.f};
        c[1] = (f32x4){0.f, 0.f, 0.f, 0.f};
#pragma unroll
        for (int kc = 0; kc < 128; kc += 32) {
            const bf16x8 af = *(const bf16x8*)(&accs[p][ar][kc + lq * 8]);
#pragma unroll
            for (int sn = 0; sn < 2; sn++) {
                const bf16x8 b = *(const bf16x8*)(B + (size_t)(wave * 32 + sn * 16 + lm) * 128 + kc + lq * 8);
                c[sn] = __builtin_amdgcn_mfma_f32_16x16x32_bf16(af, b, c[sn], 0, 0, 0);
            }
        }
#pragma unroll
        for (int sn = 0; sn < 2; sn++) {
            if (p == 0)      e0[sn] += c[sn] * c[sn];
            else if (p < 4)  e1[sn] += c[sn] * c[sn];
            else if (p == 4 || p == 7 || p == 9) { e2[sn] += c[sn] * c[sn]; trv[sn] += c[sn]; }
            else             e2[sn] += 2.0f * c[sn] * c[sn];
        }
    }
    __syncthreads();   // accs dead -> xs alias becomes writable

    // ---- combine + gate
    if (lq < 2) {
#pragma unroll
        for (int sn = 0; sn < 2; sn++) {
            const int g = wave * 32 + sn * 16 + lm;
#pragma unroll
            for (int r = 0; r < 4; r++) {
                const int node = lq * 4 + r;
                const float s0 = bf2f(scal_s[node][3 * g + 0]);
                const float s1 = bf2f(scal_s[node][3 * g + 1]);
                const float s2 = bf2f(scal_s[node][3 * g + 2]);
                xs[node][g]       = 3.0f * e0[sn][r] * s0 * s0;
                xs[node][128 + g] = 2.0f * e1[sn][r] * s1 * s1;
                const float tr = trv[sn][r];
                xs[node][256 + g] = (e2[sn][r] - tr * tr * (1.0f / 3.0f)) * s2 * s2;
            }
        }
    }
    __syncthreads();

    // ---- LN(384): wave w normalizes nodes {2w, 2w+1}
#pragma unroll
    for (int i = 0; i < 2; i++) {
        const int node = wave * 2 + i;
        float v[6];
        float s = 0.f;
#pragma unroll
        for (int j = 0; j < 6; j++) { v[j] = xs[node][lane + 64 * j]; s += v[j]; }
#pragma unroll
        for (int o = 1; o < 64; o <<= 1) s += __shfl_xor(s, o, 64);
        const float mu = s * (1.0f / 384.0f);
        float q = 0.f;
#pragma unroll
        for (int j = 0; j < 6; j++) { v[j] -= mu; q += v[j] * v[j]; }
#pragma unroll
        for (int o = 1; o < 64; o <<= 1) q += __shfl_xor(q, o, 64);
        const float rs = rsqrtf(q * (1.0f / 384.0f) + 1e-5f);
#pragma unroll
        for (int j = 0; j < 6; j++) {
            const int col = lane + 64 * j;
            xs[node][col] = v[j] * rs * outn_g[col] + outn_b[col];
        }
    }
    __syncthreads();

    // ---- lin (ss aliases h1; h1 dead)
    {
        const int j = tid & 127, half = tid >> 7;
        float a4[4];
        const float lb = lin_b[j];
#pragma unroll
        for (int i = 0; i < 4; i++) a4[i] = lb;
        const float4* wr = (const float4*)(lin_w + j * 384);
#pragma unroll 2
        for (int k4 = 0; k4 < 96; k4++) {
            const float4 w4 = wr[k4];
#pragma unroll
            for (int i = 0; i < 4; i++) {
                const float4 xv = *(const float4*)&xs[half * 4 + i][k4 * 4];
                a4[i] += w4.x * xv.x + w4.y * xv.y + w4.z * xv.z + w4.w * xv.w;
            }
        }
        __syncthreads();   // h1 fully dead before ss writes
#pragma unroll
        for (int i = 0; i < 4; i++) ss[half * 4 + i][j] = silu(a4[i]);
    }
    __syncthreads();

    // ---- ol1 + ol2
    {
        const int o = tid & 63, q = tid >> 6;
        float a2v[2];
        const float ob = ol1_b[o];
        a2v[0] = ob; a2v[1] = ob;
        const float4* o4 = (const float4*)(ol1_w + o * 128);
#pragma unroll 4
        for (int k4 = 0; k4 < 32; k4++) {
            const float4 w4 = o4[k4];
#pragma unroll
            for (int i = 0; i < 2; i++) {
                const float4 sv = *(const float4*)&ss[q * 2 + i][k4 * 4];
                a2v[i] += w4.x * sv.x + w4.y * sv.y + w4.z * sv.z + w4.w * sv.w;
            }
        }
        const float w2 = ol2_w[o];
#pragma unroll
        for (int i = 0; i < 2; i++) {
            float v = silu(a2v[i]) * w2;
            for (int s = 32; s > 0; s >>= 1) v += __shfl_down(v, s, 64);
            if (o == 0) out[n0 + q * 2 + i] = v + ol2_b[0];
        }
    }
}

// ---------------------------------------------------------------------------
extern "C" void kernel_launch(void* const* d_in, const int* in_sizes, int n_in,
                              void* d_out, int out_size, void* d_ws, size_t ws_size,
                              hipStream_t stream) {
    (void)in_sizes; (void)n_in; (void)out_size; (void)ws_size;
    const float* edge_vec = (const float*)d_in[0];
    const float* emb_w   = (const float*)d_in[1];
    const float* emb2_w  = (const float*)d_in[2];
    const float* emb2_b  = (const float*)d_in[3];
    const float* dp1_w   = (const float*)d_in[4];
    const float* dp1_b   = (const float*)d_in[5];
    const float* dp2_w   = (const float*)d_in[6];
    const float* dp2_b   = (const float*)d_in[7];
    const float* dp3_w   = (const float*)d_in[8];
    const float* dp3_b   = (const float*)d_in[9];
    const float* lt0_w   = (const float*)d_in[10];
    const float* lt1_w   = (const float*)d_in[11];
    const float* lt2_w   = (const float*)d_in[12];
    const float* ls0_w   = (const float*)d_in[13];
    const float* ls0_b   = (const float*)d_in[14];
    const float* ls1_w   = (const float*)d_in[15];
    const float* ls1_b   = (const float*)d_in[16];
    const float* init_g  = (const float*)d_in[17];
    const float* init_b  = (const float*)d_in[18];
    const float* lin_w   = (const float*)d_in[19];
    const float* lin_b   = (const float*)d_in[20];
    const float* outn_g  = (const float*)d_in[21];
    const float* outn_b  = (const float*)d_in[22];
    const float* ol1_w   = (const float*)d_in[23];
    const float* ol1_b   = (const float*)d_in[24];
    const float* ol2_w   = (const float*)d_in[25];
    const float* ol2_b   = (const float*)d_in[26];
    const int* z  = (const int*)d_in[27];
    const int* ei = (const int*)d_in[28];
    float* out = (float*)d_out;

    char* w = (char*)d_ws;
    int*            cursor    = (int*)(w);                      // -> 16384
    unsigned short* wb        = (unsigned short*)(w + 16384);   // -> 401408
    float*          U1        = (float*)(w + 401408);           // -> 466944
    float*          U2        = (float*)(w + 466944);           // -> 532480
    int*            order_pad = (int*)(w + 532480);             // -> 1581056

    hipMemsetAsync(w, 0, 16384, stream);  // cursor
    k_setup<<<dim3(4540), dim3(256), 0, stream>>>(emb_w, emb2_w, ei, z,
                                                  ls0_w, ls1_w, lt0_w, lt1_w, lt2_w,
                                                  dp1_w, dp2_w, dp3_w,
                                                  U1, U2, cursor, order_pad, wb);
    k_fused<<<dim3(512), dim3(256), 0, stream>>>(z, cursor, order_pad, edge_vec,
                                                 U1, U2, emb2_b, dp1_b, dp2_b, dp3_b, wb,
                                                 init_g, init_b, ls0_b, ls1_b,
                                                 outn_g, outn_b, lin_w, lin_b,
                                                 ol1_w, ol1_b, ol2_w, ol2_b, out);
}